// Round 7
// baseline (469.672 us; speedup 1.0000x reference)
//
#include <hip/hip_runtime.h>
#include <cstdint>
#include <cstddef>

// Problem constants (fixed by reference setup_inputs)
#define HW_      65536     // 256*256
#define NB       8         // batch
#define NC       8         // colour dim
#define NF       64        // feature dim
#define NK       8         // K_STEPS
#define NT       512       // threads per block (8 waves)
#define PX       4         // pixels per thread (float4)
#define CHUNK_PX (NT * PX)        // 2048 px per block
#define NCH      (HW_ / CHUNK_PX) // 32 blocks per batch -> 256 blocks total (1/CU)
#define NWAVE    (NT / 64)

// log(0.01f), log(0.99f)
#define LN_LO  (-4.6051702f)
#define LN_HI  (-0.010050336f)

#define LMK_SZ ((size_t)(NK + 1) * NB * HW_)
#define COL_SZ ((size_t)NB * NC * HW_)

typedef unsigned long long u64;
typedef unsigned int       u32;

// ws layout (memset to 0 each call):
//   slots    u64[NK][NB]       @ 0     : packed argmax winner per (step,batch)
//   seedbits u32[NK][NB][NC]   @ 512   : seed floats (bit pattern) per (step,batch)
//   arrive1  u32[NK][NB]       @ 2560  : argmax publish counters (target NCH)
//   arrive2  u32[NK][NB]       @ 2816  : seed publish flags (target 1)
#define WS_SLOTS    0
#define WS_SEEDBITS 512
#define WS_ARRIVE1  2560
#define WS_ARRIVE2  2816
#define WS_BYTES    3072

// Packed argmax candidate: high 32 = float bits of p (p >= 0 -> order-preserving),
// low 32 = ~idx so equal p prefers the SMALLER index (jnp.argmax tie-break).
__device__ __forceinline__ u64 pack_pi(float v, int idx) {
    return ((u64)__float_as_uint(v) << 32) | (unsigned)(~(unsigned)idx);
}
__device__ __forceinline__ int unpack_idx(u64 p) {
    return (int)(~(unsigned)(p & 0xffffffffull));
}

__device__ __forceinline__ void argmax_cmp(float& bv, int& bi, float ov, int oi) {
    if (ov > bv || (ov == bv && oi < bi)) { bv = ov; bi = oi; }
}

__device__ __forceinline__ void wave_argmax(float& bv, int& bi) {
#pragma unroll
    for (int off = 32; off > 0; off >>= 1) {
        float ov = __shfl_down(bv, off);
        int   oi = __shfl_down(bi, off);
        argmax_cmp(bv, bi, ov, oi);
    }
}

// Bounded acquire-spin until *p >= target (bailout instead of hang).
__device__ __forceinline__ void spin_ge(u32* p, u32 target) {
    for (int it = 0; it < (1 << 24); ++it) {
        if (__hip_atomic_load(p, __ATOMIC_ACQUIRE, __HIP_MEMORY_SCOPE_AGENT) >= target)
            return;
        __builtin_amdgcn_s_sleep(1);
    }
}

// ---------------------------------------------------------------------------
// One cooperative kernel: colour head + 8 scan steps, per-batch atomic barriers.
// ---------------------------------------------------------------------------
__global__ __launch_bounds__(NT)
void fused_sbp_kernel(const float* __restrict__ feat, const float* __restrict__ Wm,
                      const float* __restrict__ bias, const float* __restrict__ log_sigma_p,
                      const float* __restrict__ rand_pix,
                      float* __restrict__ log_m_k, float* __restrict__ log_s_k,
                      float* __restrict__ colour, float* __restrict__ seeds,
                      u64* __restrict__ slots, u32* __restrict__ seedbits,
                      u32* __restrict__ arrive1, u32* __restrict__ arrive2) {
    __shared__ float sW[NC * NF];
    __shared__ float sB[NC];
    __shared__ float sSeed[NC];
    __shared__ float swv[NWAVE];
    __shared__ int   swi[NWAVE];
    __shared__ int   sResI;

    const int tid = threadIdx.x, lane = tid & 63, wid = tid >> 6;
    const int chunk = blockIdx.x, b = blockIdx.y;

    for (int i = tid; i < NC * NF; i += NT) sW[i] = Wm[i];
    if (tid < NC) sB[tid] = bias[tid];
    __syncthreads();

    const int    hw0  = chunk * CHUNK_PX + tid * PX;
    const size_t base = (size_t)b * HW_ + hw0;
    const float  inv_sigma = expf(-log_sigma_p[0]);

    float4 r4 = *reinterpret_cast<const float4*>(rand_pix + base);

    // ---- colour head: keep my 4 pixels x 8 channels in registers ----
    float4 col4[NC];
#pragma unroll
    for (int c = 0; c < NC; ++c) col4[c] = make_float4(0.f, 0.f, 0.f, 0.f);

    const float* fb = feat + (size_t)b * NF * HW_ + hw0;
    for (int f = 0; f < NF; ++f) {
        float4 v = *reinterpret_cast<const float4*>(fb + (size_t)f * HW_);
#pragma unroll
        for (int c = 0; c < NC; ++c) {
            float w = sW[c * NF + f];
            col4[c].x = fmaf(v.x, w, col4[c].x);
            col4[c].y = fmaf(v.y, w, col4[c].y);
            col4[c].z = fmaf(v.z, w, col4[c].z);
            col4[c].w = fmaf(v.w, w, col4[c].w);
        }
    }
    {
        float* cb = colour + (size_t)b * NC * HW_ + hw0;
#pragma unroll
        for (int c = 0; c < NC; ++c) {
            float bc = sB[c];
            col4[c].x += bc; col4[c].y += bc; col4[c].z += bc; col4[c].w += bc;
            *reinterpret_cast<float4*>(cb + (size_t)c * HW_) = col4[c];
        }
    }

    // log_s_k[0] = 0
    *reinterpret_cast<float4*>(log_s_k + base) = make_float4(0.f, 0.f, 0.f, 0.f);
    float ls[PX] = {0.f, 0.f, 0.f, 0.f};
    float rp[PX] = {r4.x, r4.y, r4.z, r4.w};

    // ---- publish step-0 argmax candidate (scope == 1 -> p = rand) ----
    {
        float bv = rp[0]; int bi = hw0;
        argmax_cmp(bv, bi, rp[1], hw0 + 1);
        argmax_cmp(bv, bi, rp[2], hw0 + 2);
        argmax_cmp(bv, bi, rp[3], hw0 + 3);
        wave_argmax(bv, bi);
        if (lane == 0) { swv[wid] = bv; swi[wid] = bi; }
        __syncthreads();
        if (tid == 0) {
            float v = swv[0]; int ii = swi[0];
#pragma unroll
            for (int w = 1; w < NWAVE; ++w) argmax_cmp(v, ii, swv[w], swi[w]);
            atomicMax(&slots[0 * NB + b], pack_pi(v, ii));
            __hip_atomic_fetch_add(&arrive1[0 * NB + b], 1u,
                                   __ATOMIC_RELEASE, __HIP_MEMORY_SCOPE_AGENT);
        }
    }

    // ---- 8 scan steps, barriers per batch only ----
    for (int k = 0; k < NK; ++k) {
        // wait until all 32 blocks of this batch published, then read winner
        if (tid == 0) {
            spin_ge(&arrive1[k * NB + b], NCH);
            u64 pk = __hip_atomic_load(&slots[k * NB + b], __ATOMIC_RELAXED,
                                       __HIP_MEMORY_SCOPE_AGENT);
            sResI = unpack_idx(pk);
        }
        __syncthreads();
        const int idx = sResI;

        // winner block (owns pixel idx) publishes the seed from registers
        if ((idx >> 11) == chunk) {          // CHUNK_PX == 2048
            const int owner = (idx & (CHUNK_PX - 1)) >> 2;
            if (tid == owner) {
                const int p = idx & 3;
#pragma unroll
                for (int c = 0; c < NC; ++c) {
                    float sv = (p == 0) ? col4[c].x : (p == 1) ? col4[c].y
                             : (p == 2) ? col4[c].z : col4[c].w;
                    __hip_atomic_store(&seedbits[(k * NB + b) * NC + c],
                                       __float_as_uint(sv),
                                       __ATOMIC_RELAXED, __HIP_MEMORY_SCOPE_AGENT);
                    seeds[((size_t)k * NB + b) * NC + c] = sv;
                }
                __hip_atomic_fetch_add(&arrive2[k * NB + b], 1u,
                                       __ATOMIC_RELEASE, __HIP_MEMORY_SCOPE_AGENT);
            }
        }
        if (tid == 0) spin_ge(&arrive2[k * NB + b], 1u);
        __syncthreads();
        if (tid < NC)
            sSeed[tid] = __uint_as_float(
                __hip_atomic_load(&seedbits[(k * NB + b) * NC + tid],
                                  __ATOMIC_ACQUIRE, __HIP_MEMORY_SCOPE_AGENT));
        __syncthreads();

        // per-pixel update (registers only)
        float lm[PX], ln_[PX];
#pragma unroll
        for (int p = 0; p < PX; ++p) {
            float d = 0.f;
#pragma unroll
            for (int c = 0; c < NC; ++c) {
                float cvp = (p == 0) ? col4[c].x : (p == 1) ? col4[c].y
                          : (p == 2) ? col4[c].z : col4[c].w;
                float diff = cvp - sSeed[c];
                d = fmaf(diff, diff, d);
            }
            float t  = -d * inv_sigma;                 // log(alpha) pre-clamp
            float tc = fminf(fmaxf(t, LN_LO), LN_HI);  // log(clip(alpha))
            float a  = expf(tc);
            lm[p]  = ls[p] + tc;
            ln_[p] = ls[p] + logf(1.0f - a);
        }

        *reinterpret_cast<float4*>(log_m_k + (size_t)k * NB * HW_ + base) =
            make_float4(lm[0], lm[1], lm[2], lm[3]);
        *reinterpret_cast<float4*>(log_s_k + (size_t)(k + 1) * NB * HW_ + base) =
            make_float4(ln_[0], ln_[1], ln_[2], ln_[3]);
#pragma unroll
        for (int p = 0; p < PX; ++p) ls[p] = ln_[p];

        if (k == NK - 1) {
            // log_m_k[K] = last_log_s
            *reinterpret_cast<float4*>(log_m_k + (size_t)NK * NB * HW_ + base) =
                make_float4(ln_[0], ln_[1], ln_[2], ln_[3]);
        } else {
            // publish next step's argmax candidate: p = rand * exp(log_s_new)
            float bv = rp[0] * expf(ln_[0]); int bi = hw0;
            argmax_cmp(bv, bi, rp[1] * expf(ln_[1]), hw0 + 1);
            argmax_cmp(bv, bi, rp[2] * expf(ln_[2]), hw0 + 2);
            argmax_cmp(bv, bi, rp[3] * expf(ln_[3]), hw0 + 3);
            wave_argmax(bv, bi);
            if (lane == 0) { swv[wid] = bv; swi[wid] = bi; }
            __syncthreads();
            if (tid == 0) {
                float v = swv[0]; int ii = swi[0];
#pragma unroll
                for (int w = 1; w < NWAVE; ++w) argmax_cmp(v, ii, swv[w], swi[w]);
                atomicMax(&slots[(k + 1) * NB + b], pack_pi(v, ii));
                __hip_atomic_fetch_add(&arrive1[(k + 1) * NB + b], 1u,
                                       __ATOMIC_RELEASE, __HIP_MEMORY_SCOPE_AGENT);
            }
        }
    }
}

// ---------------------------------------------------------------------------
extern "C" void kernel_launch(void* const* d_in, const int* in_sizes, int n_in,
                              void* d_out, int out_size, void* d_ws, size_t ws_size,
                              hipStream_t stream) {
    const float* feat      = (const float*)d_in[0];  // [8,64,256,256]
    const float* Wm        = (const float*)d_in[1];  // [8,64]
    const float* bias      = (const float*)d_in[2];  // [8]
    const float* log_sigma = (const float*)d_in[3];  // [1]
    const float* rand_pix  = (const float*)d_in[4];  // [8,1,256,256]
    // d_in[5] = steps_to_run (== NK, fixed)

    float* out     = (float*)d_out;
    float* log_m_k = out;              // (NK+1)*NB*HW_
    float* log_s_k = out + LMK_SZ;     // (NK+1)*NB*HW_
    float* colour  = out + 2 * LMK_SZ; // NB*NC*HW_
    float* seeds   = colour + COL_SZ;  // NK*NB*NC

    char* ws = (char*)d_ws;
    u64* slots    = (u64*)(ws + WS_SLOTS);
    u32* seedbits = (u32*)(ws + WS_SEEDBITS);
    u32* arrive1  = (u32*)(ws + WS_ARRIVE1);
    u32* arrive2  = (u32*)(ws + WS_ARRIVE2);

    hipMemsetAsync(ws, 0, WS_BYTES, stream);

    void* args[] = {
        (void*)&feat, (void*)&Wm, (void*)&bias, (void*)&log_sigma, (void*)&rand_pix,
        (void*)&log_m_k, (void*)&log_s_k, (void*)&colour, (void*)&seeds,
        (void*)&slots, (void*)&seedbits, (void*)&arrive1, (void*)&arrive2,
    };
    hipLaunchCooperativeKernel((const void*)fused_sbp_kernel,
                               dim3(NCH, NB), dim3(NT), args, 0, stream);
}

// Round 9
// 262.886 us; speedup vs baseline: 1.7866x; 1.7866x over previous
//
#include <hip/hip_runtime.h>
#include <cstdint>
#include <cstddef>

// Problem constants (fixed by reference setup_inputs)
#define HW_      65536     // 256*256
#define NB       8         // batch
#define NC       8         // colour dim
#define NF       64        // feature dim
#define NK       8         // K_STEPS
#define NT       256       // threads per block
#define PX       4         // pixels per thread (float4)
#define CHUNK_PX (NT * PX)        // 1024 px per block
#define NCH      (HW_ / CHUNK_PX) // 64 blocks per batch -> 512 blocks total

// log(0.01f), log(0.99f)
#define LN_LO  (-4.6051702f)
#define LN_HI  (-0.010050336f)

#define LMK_SZ ((size_t)(NK + 1) * NB * HW_)
#define COL_SZ ((size_t)NB * NC * HW_)

__device__ __forceinline__ void argmax_cmp(float& bv, int& bi, float ov, int oi) {
    if (ov > bv || (ov == bv && oi < bi)) { bv = ov; bi = oi; }
}

__device__ __forceinline__ void wave_argmax(float& bv, int& bi) {
#pragma unroll
    for (int off = 32; off > 0; off >>= 1) {
        float ov = __shfl_down(bv, off);
        int   oi = __shfl_down(bi, off);
        argmax_cmp(bv, bi, ov, oi);
    }
}

// Block argmax (4 waves) -> partial slot write. swv/swi are NT/64 entries.
__device__ __forceinline__ void block_argmax_store(float bv, int bi,
                                                   float* __restrict__ pv_slot,
                                                   int* __restrict__ pi_slot,
                                                   float* swv, int* swi,
                                                   int tid, int lane, int wid) {
    wave_argmax(bv, bi);
    if (lane == 0) { swv[wid] = bv; swi[wid] = bi; }
    __syncthreads();
    if (tid == 0) {
        float v = swv[0]; int ii = swi[0];
#pragma unroll
        for (int w = 1; w < NT / 64; ++w) argmax_cmp(v, ii, swv[w], swi[w]);
        *pv_slot = v;
        *pi_slot = ii;
    }
}

// ---------------------------------------------------------------------------
// Kernel 1: colour = einsum('bfhw,cf->bchw', features, W) + b
//           + fused step-0 argmax partial (scope == 1 -> p = rand)
// ---------------------------------------------------------------------------
__global__ __launch_bounds__(NT)
void colour_init_kernel(const float* __restrict__ feat, const float* __restrict__ Wm,
                        const float* __restrict__ bias, const float* __restrict__ rand_pix,
                        float* __restrict__ colour,
                        float* __restrict__ pv, int* __restrict__ pi) {
    __shared__ float sW[NC * NF];
    __shared__ float sB[NC];
    __shared__ float swv[NT / 64];
    __shared__ int   swi[NT / 64];
    const int tid = threadIdx.x, lane = tid & 63, wid = tid >> 6;
    for (int i = tid; i < NC * NF; i += NT) sW[i] = Wm[i];
    if (tid < NC) sB[tid] = bias[tid];
    __syncthreads();

    const int b   = blockIdx.y;
    const int chunk = blockIdx.x;
    const int hw0 = chunk * CHUNK_PX + tid * PX;
    const float* fb = feat + (size_t)b * NF * HW_ + hw0;

    // rand load issued early (independent of the f-loop)
    float4 r = *reinterpret_cast<const float4*>(rand_pix + (size_t)b * HW_ + hw0);

    float4 acc[NC];
#pragma unroll
    for (int c = 0; c < NC; ++c) acc[c] = make_float4(0.f, 0.f, 0.f, 0.f);

    for (int f = 0; f < NF; ++f) {
        float4 v = *reinterpret_cast<const float4*>(fb + (size_t)f * HW_);
#pragma unroll
        for (int c = 0; c < NC; ++c) {
            float w = sW[c * NF + f];
            acc[c].x = fmaf(v.x, w, acc[c].x);
            acc[c].y = fmaf(v.y, w, acc[c].y);
            acc[c].z = fmaf(v.z, w, acc[c].z);
            acc[c].w = fmaf(v.w, w, acc[c].w);
        }
    }

    float* cb = colour + (size_t)b * NC * HW_ + hw0;
#pragma unroll
    for (int c = 0; c < NC; ++c) {
        float4 o = acc[c];
        float bc = sB[c];
        o.x += bc; o.y += bc; o.z += bc; o.w += bc;
        *reinterpret_cast<float4*>(cb + (size_t)c * HW_) = o;
    }

    // fused init argmax partial: p = rand (scope == 1)
    float bv = r.x; int bi = hw0;
    argmax_cmp(bv, bi, r.y, hw0 + 1);
    argmax_cmp(bv, bi, r.z, hw0 + 2);
    argmax_cmp(bv, bi, r.w, hw0 + 3);
    block_argmax_store(bv, bi, &pv[b * NCH + chunk], &pi[b * NCH + chunk],
                       swv, swi, tid, lane, wid);
}

// ---------------------------------------------------------------------------
// Kernel 2: one scan step (4 px/thread, 512 blocks, 64 partials/batch).
//  head: wave 0 reduces 64 partials -> idx; 8 threads gather seed
//  body: dist/alpha/log updates (registers)
//  tail: block argmax partial of p = rand * exp(log_s_new) for the next step
// ---------------------------------------------------------------------------
__global__ __launch_bounds__(NT)
void step_kernel(const float* __restrict__ colour, const float* __restrict__ rand_pix,
                 const float* __restrict__ log_sigma_p,
                 float* __restrict__ log_m_k, float* __restrict__ log_s_k,
                 float* __restrict__ seeds,
                 const float* __restrict__ pv_in, const int* __restrict__ pi_in,
                 float* __restrict__ pv_out, int* __restrict__ pi_out,
                 int k) {
    const int b = blockIdx.y, chunk = blockIdx.x, tid = threadIdx.x;
    const int lane = tid & 63, wid = tid >> 6;

    const int    hw0  = chunk * CHUNK_PX + tid * PX;
    const size_t base = (size_t)b * HW_ + hw0;

    __shared__ float sSeed[NC];
    __shared__ float swv[NT / 64];
    __shared__ int   swi[NT / 64];
    __shared__ int   sResI;

    // ---- bulk independent loads issued first (hide under head reduce) ----
    float4 cv[NC];
    const float* cbp = colour + (size_t)b * NC * HW_ + hw0;
#pragma unroll
    for (int c = 0; c < NC; ++c)
        cv[c] = *reinterpret_cast<const float4*>(cbp + (size_t)c * HW_);
    float4 r4 = *reinterpret_cast<const float4*>(rand_pix + base);
    float4 ls4;
    if (k == 0) {
        ls4 = make_float4(0.f, 0.f, 0.f, 0.f);
        *reinterpret_cast<float4*>(log_s_k + base) = ls4;   // log_s_k[0] = 0
    } else {
        ls4 = *reinterpret_cast<const float4*>(log_s_k + (size_t)k * NB * HW_ + base);
    }
    const float inv_sigma = expf(-log_sigma_p[0]);

    // ---- head: wave 0 reduces the 64 partials for this batch ----
    if (wid == 0) {
        float v0 = pv_in[b * NCH + lane];
        int   i0 = pi_in[b * NCH + lane];
        wave_argmax(v0, i0);
        if (lane == 0) sResI = i0;
    }
    __syncthreads();
    const int idx = sResI;

    if (tid < NC) {
        float sc = colour[((size_t)b * NC + tid) * HW_ + idx];
        sSeed[tid] = sc;
        if (chunk == 0) seeds[((size_t)k * NB + b) * NC + tid] = sc;
    }
    __syncthreads();

    // ---- per-pixel update ----
    float ls[PX] = {ls4.x, ls4.y, ls4.z, ls4.w};
    float rp[PX] = {r4.x, r4.y, r4.z, r4.w};
    float lm[PX], ln_[PX];
#pragma unroll
    for (int p = 0; p < PX; ++p) {
        float d = 0.f;
#pragma unroll
        for (int c = 0; c < NC; ++c) {
            float cvp = (p == 0) ? cv[c].x : (p == 1) ? cv[c].y : (p == 2) ? cv[c].z : cv[c].w;
            float diff = cvp - sSeed[c];
            d = fmaf(diff, diff, d);
        }
        float t  = -d * inv_sigma;                    // log(alpha) pre-clamp
        float tc = fminf(fmaxf(t, LN_LO), LN_HI);     // log(clip(alpha))
        float a  = expf(tc);
        lm[p]  = ls[p] + tc;
        ln_[p] = ls[p] + logf(1.0f - a);
    }

    *reinterpret_cast<float4*>(log_m_k + (size_t)k * NB * HW_ + base) =
        make_float4(lm[0], lm[1], lm[2], lm[3]);
    *reinterpret_cast<float4*>(log_s_k + (size_t)(k + 1) * NB * HW_ + base) =
        make_float4(ln_[0], ln_[1], ln_[2], ln_[3]);

    if (k == NK - 1) {
        // log_m_k[K] = last_log_s
        *reinterpret_cast<float4*>(log_m_k + (size_t)NK * NB * HW_ + base) =
            make_float4(ln_[0], ln_[1], ln_[2], ln_[3]);
    } else {
        // ---- tail: partial argmax for next step: p = rand * exp(log_s_new) ----
        float bv = rp[0] * expf(ln_[0]); int bi = hw0;
        argmax_cmp(bv, bi, rp[1] * expf(ln_[1]), hw0 + 1);
        argmax_cmp(bv, bi, rp[2] * expf(ln_[2]), hw0 + 2);
        argmax_cmp(bv, bi, rp[3] * expf(ln_[3]), hw0 + 3);
        block_argmax_store(bv, bi, &pv_out[b * NCH + chunk], &pi_out[b * NCH + chunk],
                           swv, swi, tid, lane, wid);
    }
}

// ---------------------------------------------------------------------------
extern "C" void kernel_launch(void* const* d_in, const int* in_sizes, int n_in,
                              void* d_out, int out_size, void* d_ws, size_t ws_size,
                              hipStream_t stream) {
    const float* feat      = (const float*)d_in[0];  // [8,64,256,256]
    const float* Wm        = (const float*)d_in[1];  // [8,64]
    const float* bias      = (const float*)d_in[2];  // [8]
    const float* log_sigma = (const float*)d_in[3];  // [1]
    const float* rand_pix  = (const float*)d_in[4];  // [8,1,256,256]
    // d_in[5] = steps_to_run (== NK, fixed)

    float* out     = (float*)d_out;
    float* log_m_k = out;              // (NK+1)*NB*HW_
    float* log_s_k = out + LMK_SZ;     // (NK+1)*NB*HW_
    float* colour  = out + 2 * LMK_SZ; // NB*NC*HW_
    float* seeds   = colour + COL_SZ;  // NK*NB*NC

    // workspace: double-buffered argmax partials [2][NB][NCH]
    float* pv = (float*)d_ws;
    int*   pi = (int*)((char*)d_ws + 2 * NB * NCH * sizeof(float));

    dim3 grid(NCH, NB);
    colour_init_kernel<<<grid, NT, 0, stream>>>(feat, Wm, bias, rand_pix, colour,
                                                pv, pi);

    for (int k = 0; k < NK; ++k) {
        int cur = k & 1, nxt = cur ^ 1;
        step_kernel<<<grid, NT, 0, stream>>>(
            colour, rand_pix, log_sigma,
            log_m_k, log_s_k, seeds,
            pv + cur * NB * NCH, pi + cur * NB * NCH,
            pv + nxt * NB * NCH, pi + nxt * NB * NCH,
            k);
    }
}